// Round 14
// baseline (107.489 us; speedup 1.0000x reference)
//
#include <hip/hip_runtime.h>

// Bahdanau additive attention: B=8, TE=512, TD=256, H=256, fp32.
//   We = enc @ W_a; Uh = dec @ U_a
//   e[b,j,i] = softmax_i( sum_h V[h]*tanh(We[b,i,h]+Uh[b,j,h]) )
//   c[b,j,h] = sum_i e[b,j,i]*enc[b,i,h]
// d_out = [c (B*TD*H)] ++ [e (B*TD*TE)]
//
// R22 (this round): CLEAN CONVOY TEST. R19's stagger was voided by SMEM
// demotion (compiler can't prove threadIdx.x>>6 uniform -> u/v fell to
// per-lane VMEM, SGPR 112->32). Fix: qoff = readfirstlane(wv*8) -- SGPR-
// pinned, provably uniform -> u/v stay s_loads while each wave starts its
// q-loop (and phase-B k-loop) at a different offset. Convoy (all waves
// issuing identical load bursts from a common barrier, stalling in
// lockstep) is the one mechanism consistent with 12 rounds of nulls.
// Verification gate: SGPR_Count >= 80. If null with that gate passed,
// the mechanism space is exhausted -> plateau next round.
// R21 keeps: fp16 W4 stream (halved bytes, best total 106.6).
// R15 keeps: 2-kernel config, fused weight-transpose k_pre.
// R11 keeps: 2-deep named-reg prefetch. R9: split-bf16 MFMA.
// R8: 4-way rcp batching. R7: XCD swizzle (b = blockIdx&7), W4 layout.

#define BB 8
#define TE 512
#define TD 256
#define HH 256

#define EXP2F(x) __builtin_amdgcn_exp2f(x)
#define RCPF(x)  __builtin_amdgcn_rcpf(x)
#define KSCALE   2.8853900817779268f    // 2*log2(e)
#define NSC      (-2.8853900817779268f) // -2*log2(e)

typedef __attribute__((ext_vector_type(8))) short short8_t;  // 8 bf16 = 4 VGPR
typedef __attribute__((ext_vector_type(4))) float f32x4;     // MFMA acc

__device__ __forceinline__ unsigned short f2bf(float x) {
    unsigned int u = __float_as_uint(x);
    return (unsigned short)((u + 0x7FFFu + ((u >> 16) & 1u)) >> 16);  // RNE
}
__device__ __forceinline__ float bf2f(unsigned short h) {
    return __uint_as_float(((unsigned int)h) << 16);
}
__device__ __forceinline__ unsigned short f2h(float x) {   // v_cvt_f16_f32
    _Float16 h = (_Float16)x;
    unsigned short u;
    __builtin_memcpy(&u, &h, 2);
    return u;
}
__device__ __forceinline__ float h2f(unsigned short u) {   // v_cvt_f32_f16
    _Float16 h;
    __builtin_memcpy(&h, &u, 2);
    return (float)h;
}

// ---------------------------------------------------------------------------
// k_pre (R21, verbatim): split-bf16 MFMA GEMM over X = [enc; dec], D[h][i],
// fused weight transpose. Enc epilogue stores fp16 quads into
// W4h[b][hq][i][4]; dec epilogue stores fp32 Uhe rows.
// Fragment layouts (m89-verified):
//   A/B frags: row/col = l&15, k-octet = (l>>4)*8; D: col=l&15, row=(l>>4)*4+reg.
// ---------------------------------------------------------------------------
__global__ __launch_bounds__(256) void k_pre(
    const float* __restrict__ enc, const float* __restrict__ dec,
    const float* __restrict__ Wa,  const float* __restrict__ Ua,
    unsigned short* __restrict__ W4h, float* __restrict__ Uhe)
{
    const int t  = threadIdx.x;
    const int it = blockIdx.x >> 2;       // 0..95  (i-tile)
    const int ht = blockIdx.x & 3;        // 0..3   (h-tile)
    const int i0 = it * 64;
    const int h0 = ht * 64;
    const bool is_enc = (i0 < BB * TE);   // < 4096
    const float* X  = is_enc ? (enc + (size_t)i0 * HH)
                             : (dec + (size_t)(i0 - BB * TE) * HH);
    const float* Wg = is_enc ? Wa : Ua;

    __shared__ unsigned short At_h[64][40], At_l[64][40];
    __shared__ unsigned short Xs_h[64][40], Xs_l[64][40];
    __shared__ float T[32][66];           // fp32 W chunk, padded

    const int sr = t >> 2;                // X staging row / At pass-2 h (0..63)
    const int sq = (t & 3) * 8;           // k-octet (0,8,16,24)
    const int kr = t >> 3;                // W load k-row (0..31)
    const int hc = (t & 7) * 8;           // W load h-base (0..56)

    const int wv = t >> 6, l = t & 63;
    const int wh = (wv & 1) * 32;
    const int wi = (wv >> 1) * 32;
    const int fr = l & 15;
    const int fk = (l >> 4) * 8;
    const int rq = l >> 4;                // D row-quad

    f32x4 acc[2][2];
    #pragma unroll
    for (int a0 = 0; a0 < 2; a0++)
        #pragma unroll
        for (int a1 = 0; a1 < 2; a1++)
            acc[a0][a1] = (f32x4){0.f, 0.f, 0.f, 0.f};

    float4 x0  = *(const float4*)(X + (size_t)sr * HH + sq);
    float4 x1  = *(const float4*)(X + (size_t)sr * HH + sq + 4);
    float4 wf0 = *(const float4*)(Wg + (size_t)kr * HH + h0 + hc);
    float4 wf1 = *(const float4*)(Wg + (size_t)kr * HH + h0 + hc + 4);

    #pragma unroll
    for (int c = 0; c < 8; c++) {
        short8_t xh, xl;
        {
            unsigned short h;
            h = f2bf(x0.x); xh[0] = (short)h; xl[0] = (short)f2bf(x0.x - bf2f(h));
            h = f2bf(x0.y); xh[1] = (short)h; xl[1] = (short)f2bf(x0.y - bf2f(h));
            h = f2bf(x0.z); xh[2] = (short)h; xl[2] = (short)f2bf(x0.z - bf2f(h));
            h = f2bf(x0.w); xh[3] = (short)h; xl[3] = (short)f2bf(x0.w - bf2f(h));
            h = f2bf(x1.x); xh[4] = (short)h; xl[4] = (short)f2bf(x1.x - bf2f(h));
            h = f2bf(x1.y); xh[5] = (short)h; xl[5] = (short)f2bf(x1.y - bf2f(h));
            h = f2bf(x1.z); xh[6] = (short)h; xl[6] = (short)f2bf(x1.z - bf2f(h));
            h = f2bf(x1.w); xh[7] = (short)h; xl[7] = (short)f2bf(x1.w - bf2f(h));
        }
        __syncthreads();   // B1: prior chunk's MFMA readers done
        *(short8_t*)&Xs_h[sr][sq] = xh;
        *(short8_t*)&Xs_l[sr][sq] = xl;
        {
            float2 a, b;
            a.x = wf0.x; a.y = wf0.y; b.x = wf0.z; b.y = wf0.w;
            *(float2*)&T[kr][hc]     = a;
            *(float2*)&T[kr][hc + 2] = b;
            a.x = wf1.x; a.y = wf1.y; b.x = wf1.z; b.y = wf1.w;
            *(float2*)&T[kr][hc + 4] = a;
            *(float2*)&T[kr][hc + 6] = b;
        }
        __syncthreads();   // B2: T + Xs ready
        {
            short8_t ah_, al_;
            #pragma unroll
            for (int e = 0; e < 8; e++) {
                float f = T[sq + e][sr];
                unsigned short h = f2bf(f);
                ah_[e] = (short)h;
                al_[e] = (short)f2bf(f - bf2f(h));
            }
            *(short8_t*)&At_h[sr][sq] = ah_;
            *(short8_t*)&At_l[sr][sq] = al_;
        }
        if (c < 7) {
            const int kc = (c + 1) * 32;
            x0  = *(const float4*)(X + (size_t)sr * HH + kc + sq);
            x1  = *(const float4*)(X + (size_t)sr * HH + kc + sq + 4);
            wf0 = *(const float4*)(Wg + (size_t)(kc + kr) * HH + h0 + hc);
            wf1 = *(const float4*)(Wg + (size_t)(kc + kr) * HH + h0 + hc + 4);
        }
        __syncthreads();   // B3: At ready
        #pragma unroll
        for (int fm = 0; fm < 2; fm++) {
            short8_t a_h = *(const short8_t*)&At_h[wh + 16 * fm + fr][fk];
            short8_t a_l = *(const short8_t*)&At_l[wh + 16 * fm + fr][fk];
            #pragma unroll
            for (int fn = 0; fn < 2; fn++) {
                short8_t b_h = *(const short8_t*)&Xs_h[wi + 16 * fn + fr][fk];
                short8_t b_l = *(const short8_t*)&Xs_l[wi + 16 * fn + fr][fk];
                acc[fm][fn] = __builtin_amdgcn_mfma_f32_16x16x32_bf16(a_h, b_h, acc[fm][fn], 0, 0, 0);
                acc[fm][fn] = __builtin_amdgcn_mfma_f32_16x16x32_bf16(a_h, b_l, acc[fm][fn], 0, 0, 0);
                acc[fm][fn] = __builtin_amdgcn_mfma_f32_16x16x32_bf16(a_l, b_h, acc[fm][fn], 0, 0, 0);
            }
        }
    }

    #pragma unroll
    for (int fm = 0; fm < 2; fm++) {
        #pragma unroll
        for (int fn = 0; fn < 2; fn++) {
            f32x4 v = acc[fm][fn];
            float4 o;
            o.x = EXP2F(v[0] * KSCALE);
            o.y = EXP2F(v[1] * KSCALE);
            o.z = EXP2F(v[2] * KSCALE);
            o.w = EXP2F(v[3] * KSCALE);
            const int ig = i0 + wi + 16 * fn + fr;      // global concat row
            const int hb = h0 + wh + 16 * fm + rq * 4;  // 4 consecutive h
            if (is_enc) {
                const int b  = ig >> 9;                 // 512 enc rows per batch
                const int ib = ig & 511;
                const int hq = hb >> 2;
                ushort4 oh;
                oh.x = f2h(o.x); oh.y = f2h(o.y);
                oh.z = f2h(o.z); oh.w = f2h(o.w);
                *(ushort4*)(W4h + (((size_t)b * 64 + hq) * TE + ib) * 4) = oh;
            } else {
                const int j = ig - BB * TE;             // global dec row
                *(float4*)(Uhe + (size_t)j * HH + hb) = o;
            }
        }
    }
}

// ---------------------------------------------------------------------------
// k_attn (R22): 512 threads = 8 waves; block owns 4 consecutive j's of ONE
// batch, batch = blockIdx&7 (XCD-local).
// Phase A: wave wv starts its q-loop at qoff = READFIRSTLANE(wv*8) --
// SGPR-pinned, provably uniform, so ua/va offsets remain s_loads (check:
// SGPR_Count >= 80) while the 8 waves' load bursts are staggered across
// the iteration space. fp16 w-stream, 2-deep named-reg prefetch, wrapped.
// Softmax: waves 0-3. Phase B: same stagger on the enc k-loop.
// Accumulation order is a rotation of the same 64 terms per accumulator.
// ---------------------------------------------------------------------------
__global__ __launch_bounds__(512) void k_attn(
    const float* __restrict__ enc, const unsigned short* __restrict__ W4h,
    const float* __restrict__ Uhe, const float* __restrict__ Va,
    float* __restrict__ out_c, float* __restrict__ out_e)
{
    const int wv = threadIdx.x >> 6, lane = threadIdx.x & 63;
    const int b   = blockIdx.x & 7;           // XCD-local batch
    const int j0  = (blockIdx.x >> 3) * 4;    // 64 j-groups per batch
    const int jj0 = b * TD + j0;              // block-uniform

    __shared__ float sP[4][TE];      // 8 KB: energies -> probabilities
    __shared__ float sR[8][4][HH];   // 32 KB: phase-B partials

    const int i = (wv << 6) + lane;
    const unsigned short* wp = W4h + ((size_t)b * 64 * TE + i) * 4;
    const float* ua = Uhe + (size_t)jj0 * HH;   // block-uniform -> s_load
    const float* va = Va;                        // uniform

    // SGPR-pinned, compiler-certified-uniform per-wave stagger offset
    const int qoff = __builtin_amdgcn_readfirstlane((threadIdx.x >> 6) << 3);

    float a0 = 0.f, a1 = 0.f, a2 = 0.f, a3 = 0.f;

    // 4-way batched reciprocal:
    //   sum_k v_k/A_k = (nAB*dCD + nCD*dAB) / (dAB*dCD)
#define QSTEP(ACC, U)                                                     \
    {                                                                     \
        float A_ = fmaf(w4.x, (U).x, 1.f);                                \
        float B_ = fmaf(w4.y, (U).y, 1.f);                                \
        float C_ = fmaf(w4.z, (U).z, 1.f);                                \
        float D_ = fmaf(w4.w, (U).w, 1.f);                                \
        float dAB = A_ * B_, dCD = C_ * D_;                               \
        float nAB = fmaf(v4.x, B_, v4.y * A_);                            \
        float nCD = fmaf(v4.z, D_, v4.w * C_);                            \
        float num = fmaf(nAB, dCD, nCD * dAB);                            \
        ACC = fmaf(num, RCPF(dAB * dCD), ACC);                            \
    }

#define ASTEP(Q, WH)                                                      \
    {                                                                     \
        float4 w4;                                                        \
        w4.x = h2f((WH).x); w4.y = h2f((WH).y);                           \
        w4.z = h2f((WH).z); w4.w = h2f((WH).w);                           \
        float4 v4 = *(const float4*)(va + 4 * (Q));                       \
        float4 u0 = *(const float4*)(ua + 4 * (Q));                       \
        float4 u1 = *(const float4*)(ua + HH + 4 * (Q));                  \
        float4 u2 = *(const float4*)(ua + 2 * HH + 4 * (Q));              \
        float4 u3 = *(const float4*)(ua + 3 * HH + 4 * (Q));              \
        QSTEP(a0, u0)                                                     \
        QSTEP(a1, u1)                                                     \
        QSTEP(a2, u2)                                                     \
        QSTEP(a3, u3)                                                     \
    }

    // 2-deep software pipeline on the per-lane fp16 w-stream, wave-staggered
    ushort4 wA = *(const ushort4*)(wp + (size_t)qoff * TE * 4);
    ushort4 wB = *(const ushort4*)(wp + (size_t)((qoff + 1) & 63) * TE * 4);
    for (int s = 0; s < 64; s += 2) {
        const int q0 = (s + qoff) & 63;
        const int q1 = (s + 1 + qoff) & 63;
        const int q2 = (s + 2 + qoff) & 63;
        const int q3 = (s + 3 + qoff) & 63;
        ushort4 wC = *(const ushort4*)(wp + (size_t)q2 * TE * 4);
        ushort4 wD = *(const ushort4*)(wp + (size_t)q3 * TE * 4);
        ASTEP(q0, wA)
        ASTEP(q1, wB)
        wA = wC; wB = wD;
    }
#undef ASTEP
#undef QSTEP

    // conflict-free b32 writes (lane-stride 4B), energies in log2 domain
    sP[0][i] = NSC * a0;
    sP[1][i] = NSC * a1;
    sP[2][i] = NSC * a2;
    sP[3][i] = NSC * a3;
    __syncthreads();

    // ---- softmax: wave w in 0..3 handles j0+w ----------------------------
    if (wv < 4) {
        float ev[8];
        float m = -3.0e38f;
        #pragma unroll
        for (int k = 0; k < 8; k++) {
            ev[k] = sP[wv][lane + 64 * k];
            m = fmaxf(m, ev[k]);
        }
        #pragma unroll
        for (int off = 32; off; off >>= 1) m = fmaxf(m, __shfl_xor(m, off, 64));
        float s = 0.f;
        #pragma unroll
        for (int k = 0; k < 8; k++) { ev[k] = EXP2F(ev[k] - m); s += ev[k]; }
        #pragma unroll
        for (int off = 32; off; off >>= 1) s += __shfl_xor(s, off, 64);
        float rs = RCPF(s);
        float* oe = out_e + (size_t)(jj0 + wv) * TE;
        #pragma unroll
        for (int k = 0; k < 8; k++) {
            float p = ev[k] * rs;
            sP[wv][lane + 64 * k] = p;
            oe[lane + 64 * k] = p;
        }
    }
    __syncthreads();

    // ---- Phase B: wave w -> i in [64w, 64w+64), all 4 j, staggered -------
    const int ib = wv << 6;
    const float* eb = enc + ((size_t)b * TE + ib) * HH + 4 * lane;
    float4 c0 = {0,0,0,0}, c1 = {0,0,0,0}, c2 = {0,0,0,0}, c3 = {0,0,0,0};

#define BSTEP(K, QV)                                                      \
    {                                                                     \
        float p0 = sP[0][ib + (K)];                                       \
        float p1 = sP[1][ib + (K)];                                       \
        float p2 = sP[2][ib + (K)];                                       \
        float p3 = sP[3][ib + (K)];                                       \
        float4 q = QV;                                                    \
        c0.x = fmaf(p0, q.x, c0.x); c0.y = fmaf(p0, q.y, c0.y);           \
        c0.z = fmaf(p0, q.z, c0.z); c0.w = fmaf(p0, q.w, c0.w);           \
        c1.x = fmaf(p1, q.x, c1.x); c1.y = fmaf(p1, q.y, c1.y);           \
        c1.z = fmaf(p1, q.z, c1.z); c1.w = fmaf(p1, q.w, c1.w);           \
        c2.x = fmaf(p2, q.x, c2.x); c2.y = fmaf(p2, q.y, c2.y);           \
        c2.z = fmaf(p2, q.z, c2.z); c2.w = fmaf(p2, q.w, c2.w);           \
        c3.x = fmaf(p3, q.x, c3.x); c3.y = fmaf(p3, q.y, c3.y);           \
        c3.z = fmaf(p3, q.z, c3.z); c3.w = fmaf(p3, q.w, c3.w);           \
    }

    // 2-deep software pipeline on the per-lane enc stream, wave-staggered
    float4 qA = *(const float4*)(eb + (size_t)qoff * HH);
    float4 qB = *(const float4*)(eb + (size_t)((qoff + 1) & 63) * HH);
    for (int s = 0; s < 64; s += 2) {
        const int k0 = (s + qoff) & 63;
        const int k1 = (s + 1 + qoff) & 63;
        const int k2 = (s + 2 + qoff) & 63;
        const int k3 = (s + 3 + qoff) & 63;
        float4 qC = *(const float4*)(eb + (size_t)k2 * HH);
        float4 qD = *(const float4*)(eb + (size_t)k3 * HH);
        BSTEP(k0, qA)
        BSTEP(k1, qB)
        qA = qC; qB = qD;
    }
#undef BSTEP

    *(float4*)&sR[wv][0][4 * lane] = c0;
    *(float4*)&sR[wv][1][4 * lane] = c1;
    *(float4*)&sR[wv][2][4 * lane] = c2;
    *(float4*)&sR[wv][3][4 * lane] = c3;
    __syncthreads();

    // ---- final reduce: wave w -> (j = w&3, h-half = w>>2) ----------------
    {
        const int jr = wv & 3;
        const int h2 = (wv >> 2) * 128 + 2 * lane;
        float sx = 0.f, sy = 0.f;
        #pragma unroll
        for (int ww = 0; ww < 8; ww++) {
            float2 tv = *(const float2*)&sR[ww][jr][h2];
            sx += tv.x; sy += tv.y;
        }
        float2 o; o.x = sx; o.y = sy;
        *(float2*)(out_c + (size_t)(jj0 + jr) * HH + h2) = o;
    }
}

extern "C" void kernel_launch(void* const* d_in, const int* in_sizes, int n_in,
                              void* d_out, int out_size, void* d_ws, size_t ws_size,
                              hipStream_t stream) {
    const float* enc = (const float*)d_in[0];
    const float* dec = (const float*)d_in[1];
    const float* Wa  = (const float*)d_in[2];
    const float* Ua  = (const float*)d_in[3];
    const float* Va  = (const float*)d_in[4];

    unsigned short* W4h = (unsigned short*)d_ws;          // exp2-domain fp16 (2MB)
    float* Uhe = (float*)(W4h + (size_t)BB * 64 * TE * 4); // exp2-domain fp32 (2MB)

    float* out_c = (float*)d_out;                          // [B,TD,H]
    float* out_e = out_c + (size_t)BB * TD * HH;           // [B,TD,TE]

    k_pre<<<384, 256, 0, stream>>>(enc, dec, Wa, Ua, W4h, Uhe);
    k_attn<<<BB * TD / 4, 512, 0, stream>>>(enc, W4h, Uhe, Va, out_c, out_e);
}

// Round 15
// 106.823 us; speedup vs baseline: 1.0062x; 1.0062x over previous
//
#include <hip/hip_runtime.h>

// Bahdanau additive attention: B=8, TE=512, TD=256, H=256, fp32.
//   We = enc @ W_a; Uh = dec @ U_a
//   e[b,j,i] = softmax_i( sum_h V[h]*tanh(We[b,i,h]+Uh[b,j,h]) )
//   c[b,j,h] = sum_i e[b,j,i]*enc[b,i,h]
// d_out = [c (B*TD*H)] ++ [e (B*TD*TE)]
//
// R23 (final consolidation): revert R22's wave-stagger (null, slightly
// negative) to the best-measured configuration = R21 (106.6us).
// Mechanism ledger closed after 14 isolated experiments on k_attn's
// ~50% VALU idle: barriers, vector prefetch, SMEM<->LDS<->VMEM<->register
// operand delivery, occupancy 8/16/32 w/CU, kernel count, VALU count
// (-50%), L2 traffic (-50%), scalar width (x4), VMEM bytes (-50%),
// convoy stagger -- all null or negative. Remaining levers compute to
// <1us against +/-1.5us noise. Session plateau: 113.6 -> 106.6us.
// R21: fp16 W4 stream (w-bytes halved). R15: 2-kernel config, fused
// weight-transpose k_pre. R11: 2-deep named-reg prefetch (w, enc).
// R9: split-bf16 MFMA GEMM (C = Ah*Bh + Ah*Bl + Al*Bh).
// R8: 4-way rcp batching (14 ops + 1 rcp / 4 elems).
// R7: XCD swizzle (b = blockIdx&7), interleaved W4 layout.

#define BB 8
#define TE 512
#define TD 256
#define HH 256

#define EXP2F(x) __builtin_amdgcn_exp2f(x)
#define RCPF(x)  __builtin_amdgcn_rcpf(x)
#define KSCALE   2.8853900817779268f    // 2*log2(e)
#define NSC      (-2.8853900817779268f) // -2*log2(e)

typedef __attribute__((ext_vector_type(8))) short short8_t;  // 8 bf16 = 4 VGPR
typedef __attribute__((ext_vector_type(4))) float f32x4;     // MFMA acc

__device__ __forceinline__ unsigned short f2bf(float x) {
    unsigned int u = __float_as_uint(x);
    return (unsigned short)((u + 0x7FFFu + ((u >> 16) & 1u)) >> 16);  // RNE
}
__device__ __forceinline__ float bf2f(unsigned short h) {
    return __uint_as_float(((unsigned int)h) << 16);
}
__device__ __forceinline__ unsigned short f2h(float x) {   // v_cvt_f16_f32
    _Float16 h = (_Float16)x;
    unsigned short u;
    __builtin_memcpy(&u, &h, 2);
    return u;
}
__device__ __forceinline__ float h2f(unsigned short u) {   // v_cvt_f32_f16
    _Float16 h;
    __builtin_memcpy(&h, &u, 2);
    return (float)h;
}

// ---------------------------------------------------------------------------
// k_pre (R21, verbatim): split-bf16 MFMA GEMM over X = [enc; dec], D[h][i],
// fused weight transpose. Enc epilogue stores fp16 quads into
// W4h[b][hq][i][4]; dec epilogue stores fp32 Uhe rows.
// Fragment layouts (m89-verified):
//   A/B frags: row/col = l&15, k-octet = (l>>4)*8; D: col=l&15, row=(l>>4)*4+reg.
// ---------------------------------------------------------------------------
__global__ __launch_bounds__(256) void k_pre(
    const float* __restrict__ enc, const float* __restrict__ dec,
    const float* __restrict__ Wa,  const float* __restrict__ Ua,
    unsigned short* __restrict__ W4h, float* __restrict__ Uhe)
{
    const int t  = threadIdx.x;
    const int it = blockIdx.x >> 2;       // 0..95  (i-tile)
    const int ht = blockIdx.x & 3;        // 0..3   (h-tile)
    const int i0 = it * 64;
    const int h0 = ht * 64;
    const bool is_enc = (i0 < BB * TE);   // < 4096
    const float* X  = is_enc ? (enc + (size_t)i0 * HH)
                             : (dec + (size_t)(i0 - BB * TE) * HH);
    const float* Wg = is_enc ? Wa : Ua;

    __shared__ unsigned short At_h[64][40], At_l[64][40];
    __shared__ unsigned short Xs_h[64][40], Xs_l[64][40];
    __shared__ float T[32][66];           // fp32 W chunk, padded

    const int sr = t >> 2;                // X staging row / At pass-2 h (0..63)
    const int sq = (t & 3) * 8;           // k-octet (0,8,16,24)
    const int kr = t >> 3;                // W load k-row (0..31)
    const int hc = (t & 7) * 8;           // W load h-base (0..56)

    const int wv = t >> 6, l = t & 63;
    const int wh = (wv & 1) * 32;
    const int wi = (wv >> 1) * 32;
    const int fr = l & 15;
    const int fk = (l >> 4) * 8;
    const int rq = l >> 4;                // D row-quad

    f32x4 acc[2][2];
    #pragma unroll
    for (int a0 = 0; a0 < 2; a0++)
        #pragma unroll
        for (int a1 = 0; a1 < 2; a1++)
            acc[a0][a1] = (f32x4){0.f, 0.f, 0.f, 0.f};

    float4 x0  = *(const float4*)(X + (size_t)sr * HH + sq);
    float4 x1  = *(const float4*)(X + (size_t)sr * HH + sq + 4);
    float4 wf0 = *(const float4*)(Wg + (size_t)kr * HH + h0 + hc);
    float4 wf1 = *(const float4*)(Wg + (size_t)kr * HH + h0 + hc + 4);

    #pragma unroll
    for (int c = 0; c < 8; c++) {
        short8_t xh, xl;
        {
            unsigned short h;
            h = f2bf(x0.x); xh[0] = (short)h; xl[0] = (short)f2bf(x0.x - bf2f(h));
            h = f2bf(x0.y); xh[1] = (short)h; xl[1] = (short)f2bf(x0.y - bf2f(h));
            h = f2bf(x0.z); xh[2] = (short)h; xl[2] = (short)f2bf(x0.z - bf2f(h));
            h = f2bf(x0.w); xh[3] = (short)h; xl[3] = (short)f2bf(x0.w - bf2f(h));
            h = f2bf(x1.x); xh[4] = (short)h; xl[4] = (short)f2bf(x1.x - bf2f(h));
            h = f2bf(x1.y); xh[5] = (short)h; xl[5] = (short)f2bf(x1.y - bf2f(h));
            h = f2bf(x1.z); xh[6] = (short)h; xl[6] = (short)f2bf(x1.z - bf2f(h));
            h = f2bf(x1.w); xh[7] = (short)h; xl[7] = (short)f2bf(x1.w - bf2f(h));
        }
        __syncthreads();   // B1: prior chunk's MFMA readers done
        *(short8_t*)&Xs_h[sr][sq] = xh;
        *(short8_t*)&Xs_l[sr][sq] = xl;
        {
            float2 a, b;
            a.x = wf0.x; a.y = wf0.y; b.x = wf0.z; b.y = wf0.w;
            *(float2*)&T[kr][hc]     = a;
            *(float2*)&T[kr][hc + 2] = b;
            a.x = wf1.x; a.y = wf1.y; b.x = wf1.z; b.y = wf1.w;
            *(float2*)&T[kr][hc + 4] = a;
            *(float2*)&T[kr][hc + 6] = b;
        }
        __syncthreads();   // B2: T + Xs ready
        {
            short8_t ah_, al_;
            #pragma unroll
            for (int e = 0; e < 8; e++) {
                float f = T[sq + e][sr];
                unsigned short h = f2bf(f);
                ah_[e] = (short)h;
                al_[e] = (short)f2bf(f - bf2f(h));
            }
            *(short8_t*)&At_h[sr][sq] = ah_;
            *(short8_t*)&At_l[sr][sq] = al_;
        }
        if (c < 7) {
            const int kc = (c + 1) * 32;
            x0  = *(const float4*)(X + (size_t)sr * HH + kc + sq);
            x1  = *(const float4*)(X + (size_t)sr * HH + kc + sq + 4);
            wf0 = *(const float4*)(Wg + (size_t)(kc + kr) * HH + h0 + hc);
            wf1 = *(const float4*)(Wg + (size_t)(kc + kr) * HH + h0 + hc + 4);
        }
        __syncthreads();   // B3: At ready
        #pragma unroll
        for (int fm = 0; fm < 2; fm++) {
            short8_t a_h = *(const short8_t*)&At_h[wh + 16 * fm + fr][fk];
            short8_t a_l = *(const short8_t*)&At_l[wh + 16 * fm + fr][fk];
            #pragma unroll
            for (int fn = 0; fn < 2; fn++) {
                short8_t b_h = *(const short8_t*)&Xs_h[wi + 16 * fn + fr][fk];
                short8_t b_l = *(const short8_t*)&Xs_l[wi + 16 * fn + fr][fk];
                acc[fm][fn] = __builtin_amdgcn_mfma_f32_16x16x32_bf16(a_h, b_h, acc[fm][fn], 0, 0, 0);
                acc[fm][fn] = __builtin_amdgcn_mfma_f32_16x16x32_bf16(a_h, b_l, acc[fm][fn], 0, 0, 0);
                acc[fm][fn] = __builtin_amdgcn_mfma_f32_16x16x32_bf16(a_l, b_h, acc[fm][fn], 0, 0, 0);
            }
        }
    }

    #pragma unroll
    for (int fm = 0; fm < 2; fm++) {
        #pragma unroll
        for (int fn = 0; fn < 2; fn++) {
            f32x4 v = acc[fm][fn];
            float4 o;
            o.x = EXP2F(v[0] * KSCALE);
            o.y = EXP2F(v[1] * KSCALE);
            o.z = EXP2F(v[2] * KSCALE);
            o.w = EXP2F(v[3] * KSCALE);
            const int ig = i0 + wi + 16 * fn + fr;      // global concat row
            const int hb = h0 + wh + 16 * fm + rq * 4;  // 4 consecutive h
            if (is_enc) {
                const int b  = ig >> 9;                 // 512 enc rows per batch
                const int ib = ig & 511;
                const int hq = hb >> 2;
                ushort4 oh;
                oh.x = f2h(o.x); oh.y = f2h(o.y);
                oh.z = f2h(o.z); oh.w = f2h(o.w);
                *(ushort4*)(W4h + (((size_t)b * 64 + hq) * TE + ib) * 4) = oh;
            } else {
                const int j = ig - BB * TE;             // global dec row
                *(float4*)(Uhe + (size_t)j * HH + hb) = o;
            }
        }
    }
}

// ---------------------------------------------------------------------------
// k_attn (R21, verbatim — best measured): 512 threads = 8 waves; block owns
// 4 consecutive j's of ONE batch, batch = blockIdx&7 (XCD-local).
// Phase A: wave w -> i = 64w+lane; fp16 w-stream (ushort4, 8B/lane),
// 2-deep named-reg prefetch, 4 cvt_f32_f16 per q; u/v fp32 uniform s_loads.
// OOB prefetch at q=62 lands in the adjacent Uhe region (safe, unused).
// Softmax: waves 0-3. Phase B: 2-deep prefetch on the enc stream.
// ---------------------------------------------------------------------------
__global__ __launch_bounds__(512) void k_attn(
    const float* __restrict__ enc, const unsigned short* __restrict__ W4h,
    const float* __restrict__ Uhe, const float* __restrict__ Va,
    float* __restrict__ out_c, float* __restrict__ out_e)
{
    const int wv = threadIdx.x >> 6, lane = threadIdx.x & 63;
    const int b   = blockIdx.x & 7;           // XCD-local batch
    const int j0  = (blockIdx.x >> 3) * 4;    // 64 j-groups per batch
    const int jj0 = b * TD + j0;              // block-uniform

    __shared__ float sP[4][TE];      // 8 KB: energies -> probabilities
    __shared__ float sR[8][4][HH];   // 32 KB: phase-B partials

    const int i = (wv << 6) + lane;
    const unsigned short* wp = W4h + ((size_t)b * 64 * TE + i) * 4;
    const float* ua = Uhe + (size_t)jj0 * HH;   // block-uniform -> s_load
    const float* va = Va;                        // uniform

    float a0 = 0.f, a1 = 0.f, a2 = 0.f, a3 = 0.f;

    // 4-way batched reciprocal:
    //   sum_k v_k/A_k = (nAB*dCD + nCD*dAB) / (dAB*dCD)
#define QSTEP(ACC, U)                                                     \
    {                                                                     \
        float A_ = fmaf(w4.x, (U).x, 1.f);                                \
        float B_ = fmaf(w4.y, (U).y, 1.f);                                \
        float C_ = fmaf(w4.z, (U).z, 1.f);                                \
        float D_ = fmaf(w4.w, (U).w, 1.f);                                \
        float dAB = A_ * B_, dCD = C_ * D_;                               \
        float nAB = fmaf(v4.x, B_, v4.y * A_);                            \
        float nCD = fmaf(v4.z, D_, v4.w * C_);                            \
        float num = fmaf(nAB, dCD, nCD * dAB);                            \
        ACC = fmaf(num, RCPF(dAB * dCD), ACC);                            \
    }

#define ASTEP(Q, WH)                                                      \
    {                                                                     \
        float4 w4;                                                        \
        w4.x = h2f((WH).x); w4.y = h2f((WH).y);                           \
        w4.z = h2f((WH).z); w4.w = h2f((WH).w);                           \
        float4 v4 = *(const float4*)(va + 4 * (Q));                       \
        float4 u0 = *(const float4*)(ua + 4 * (Q));                       \
        float4 u1 = *(const float4*)(ua + HH + 4 * (Q));                  \
        float4 u2 = *(const float4*)(ua + 2 * HH + 4 * (Q));              \
        float4 u3 = *(const float4*)(ua + 3 * HH + 4 * (Q));              \
        QSTEP(a0, u0)                                                     \
        QSTEP(a1, u1)                                                     \
        QSTEP(a2, u2)                                                     \
        QSTEP(a3, u3)                                                     \
    }

    // 2-deep software pipeline on the per-lane fp16 w-stream
    ushort4 wA = *(const ushort4*)(wp);
    ushort4 wB = *(const ushort4*)(wp + (size_t)TE * 4);
    for (int q = 0; q < 64; q += 2) {
        ushort4 wC = *(const ushort4*)(wp + (size_t)(q + 2) * TE * 4);
        ushort4 wD = *(const ushort4*)(wp + (size_t)(q + 3) * TE * 4);
        ASTEP(q, wA)
        ASTEP(q + 1, wB)
        wA = wC; wB = wD;
    }
#undef ASTEP
#undef QSTEP

    // conflict-free b32 writes (lane-stride 4B), energies in log2 domain
    sP[0][i] = NSC * a0;
    sP[1][i] = NSC * a1;
    sP[2][i] = NSC * a2;
    sP[3][i] = NSC * a3;
    __syncthreads();

    // ---- softmax: wave w in 0..3 handles j0+w ----------------------------
    if (wv < 4) {
        float ev[8];
        float m = -3.0e38f;
        #pragma unroll
        for (int k = 0; k < 8; k++) {
            ev[k] = sP[wv][lane + 64 * k];
            m = fmaxf(m, ev[k]);
        }
        #pragma unroll
        for (int off = 32; off; off >>= 1) m = fmaxf(m, __shfl_xor(m, off, 64));
        float s = 0.f;
        #pragma unroll
        for (int k = 0; k < 8; k++) { ev[k] = EXP2F(ev[k] - m); s += ev[k]; }
        #pragma unroll
        for (int off = 32; off; off >>= 1) s += __shfl_xor(s, off, 64);
        float rs = RCPF(s);
        float* oe = out_e + (size_t)(jj0 + wv) * TE;
        #pragma unroll
        for (int k = 0; k < 8; k++) {
            float p = ev[k] * rs;
            sP[wv][lane + 64 * k] = p;
            oe[lane + 64 * k] = p;
        }
    }
    __syncthreads();

    // ---- Phase B: wave w -> i in [64w, 64w+64), all 4 j ------------------
    const int ib = wv << 6;
    const float* eb = enc + ((size_t)b * TE + ib) * HH + 4 * lane;
    float4 c0 = {0,0,0,0}, c1 = {0,0,0,0}, c2 = {0,0,0,0}, c3 = {0,0,0,0};

#define BSTEP(K, QV)                                                      \
    {                                                                     \
        float p0 = sP[0][ib + (K)];                                       \
        float p1 = sP[1][ib + (K)];                                       \
        float p2 = sP[2][ib + (K)];                                       \
        float p3 = sP[3][ib + (K)];                                       \
        float4 q = QV;                                                    \
        c0.x = fmaf(p0, q.x, c0.x); c0.y = fmaf(p0, q.y, c0.y);           \
        c0.z = fmaf(p0, q.z, c0.z); c0.w = fmaf(p0, q.w, c0.w);           \
        c1.x = fmaf(p1, q.x, c1.x); c1.y = fmaf(p1, q.y, c1.y);           \
        c1.z = fmaf(p1, q.z, c1.z); c1.w = fmaf(p1, q.w, c1.w);           \
        c2.x = fmaf(p2, q.x, c2.x); c2.y = fmaf(p2, q.y, c2.y);           \
        c2.z = fmaf(p2, q.z, c2.z); c2.w = fmaf(p2, q.w, c2.w);           \
        c3.x = fmaf(p3, q.x, c3.x); c3.y = fmaf(p3, q.y, c3.y);           \
        c3.z = fmaf(p3, q.z, c3.z); c3.w = fmaf(p3, q.w, c3.w);           \
    }

    // 2-deep software pipeline on the per-lane enc stream (tail clamped:
    // enc is an input buffer, no OOB reads allowed)
    float4 qA = *(const float4*)(eb);
    float4 qB = *(const float4*)(eb + (size_t)HH);
    for (int k = 0; k < 64; k += 2) {
        const int k2 = (k + 2 < 64) ? k + 2 : 62;
        const int k3 = (k + 3 < 64) ? k + 3 : 63;
        float4 qC = *(const float4*)(eb + (size_t)k2 * HH);
        float4 qD = *(const float4*)(eb + (size_t)k3 * HH);
        BSTEP(k, qA)
        BSTEP(k + 1, qB)
        qA = qC; qB = qD;
    }
#undef BSTEP

    *(float4*)&sR[wv][0][4 * lane] = c0;
    *(float4*)&sR[wv][1][4 * lane] = c1;
    *(float4*)&sR[wv][2][4 * lane] = c2;
    *(float4*)&sR[wv][3][4 * lane] = c3;
    __syncthreads();

    // ---- final reduce: wave w -> (j = w&3, h-half = w>>2) ----------------
    {
        const int jr = wv & 3;
        const int h2 = (wv >> 2) * 128 + 2 * lane;
        float sx = 0.f, sy = 0.f;
        #pragma unroll
        for (int ww = 0; ww < 8; ww++) {
            float2 tv = *(const float2*)&sR[ww][jr][h2];
            sx += tv.x; sy += tv.y;
        }
        float2 o; o.x = sx; o.y = sy;
        *(float2*)(out_c + (size_t)(jj0 + jr) * HH + h2) = o;
    }
}

extern "C" void kernel_launch(void* const* d_in, const int* in_sizes, int n_in,
                              void* d_out, int out_size, void* d_ws, size_t ws_size,
                              hipStream_t stream) {
    const float* enc = (const float*)d_in[0];
    const float* dec = (const float*)d_in[1];
    const float* Wa  = (const float*)d_in[2];
    const float* Ua  = (const float*)d_in[3];
    const float* Va  = (const float*)d_in[4];

    unsigned short* W4h = (unsigned short*)d_ws;          // exp2-domain fp16 (2MB)
    float* Uhe = (float*)(W4h + (size_t)BB * 64 * TE * 4); // exp2-domain fp32 (2MB)

    float* out_c = (float*)d_out;                          // [B,TD,H]
    float* out_e = out_c + (size_t)BB * TD * HH;           // [B,TD,TE]

    k_pre<<<384, 256, 0, stream>>>(enc, dec, Wa, Ua, W4h, Uhe);
    k_attn<<<BB * TD / 4, 512, 0, stream>>>(enc, W4h, Uhe, Va, out_c, out_e);
}